// Round 1
// 41500.696 us; speedup vs baseline: 3.3261x; 3.3261x over previous
//
#include <hip/hip_runtime.h>

// FoldedAutoencoder — fused single-kernel implementation, round 3.
// Change vs round 2: k-major PANELIZATION of the three streamed GRU weight
// matrices (W_hh0, W_ih1, W_hh1) into d_ws. The old per-thread-row dot walked
// rows 1 KiB apart across lanes -> 64 cache lines per wave load instruction
// (uncoalesced), ~97% latency stall (VALUBusy 2.4% @ 6.2% occupancy).
// Panels store P[k_chunk][row][chunk] so consecutive lanes read contiguous
// 16 B -> 8 lanes per 128B line. Summation order preserved exactly.
// Panels are built redundantly by every block (identical bytes -> race-free),
// gated on ws_size with fallback to the previous (verified) path.

typedef unsigned short u16;
typedef unsigned int u32;

__device__ __forceinline__ float b2f(u16 u) { return __uint_as_float(((u32)u) << 16); }
__device__ __forceinline__ float blo(u32 u) { return __uint_as_float(u << 16); }
__device__ __forceinline__ float bhi(u32 u) { return __uint_as_float(u & 0xffff0000u); }
__device__ __forceinline__ u16 f2b(float f) {
    u32 x = __float_as_uint(f);
    u32 r = x + 0x7fffu + ((x >> 16) & 1u);   // RNE
    return (u16)(r >> 16);
}

#define BB 64
#define SS 512
#define TWO_PI 6.28318530717958647692f
#define BIGF 3.402823466e+38f
#define PANEL_ELEMS (1536 * 512)

struct P {
    const void* lc;     // (B,3,S)
    const void* freq;   // (B,)
    const void* W[12];  // Wih0,bih0,Whh0,bhh0,Wih1,bih1,Whh1,bhh1,Wl1,bl1,Wl2,bl2
    void* out;          // (B,16)
    void* ws;
    unsigned long long ws_size;
};

struct Shm {
    float ph[512], mg[512], skey[512], sig[512], vld[512];
    int   sidx[512];
    float ps2[512], ms2[512], vs2[512];
    float h0[512], h1[512];
    float pn[50][8], pd[50][8], smoothv[50];
    float eL[33];
    float gshift, nv;
};

// dtype probe: bf16 iff all 64 u16 words of `frequency` decode into [0.4, 5.5].
__device__ __forceinline__ bool inputs_are_bf16(const void* freq) {
    const u16* q = (const u16*)freq;
    bool ok = true;
    for (int i = 0; i < 64; ++i) {
        float v = b2f(q[i]);
        ok = ok && (v >= 0.4f) && (v <= 5.5f);
    }
    return ok;
}

template<bool BF>
__device__ __forceinline__ float ldw(const void* p, size_t i) {
    if constexpr (BF) return b2f(((const u16*)p)[i]);
    else              return ((const float*)p)[i];
}

template<bool BF>
__device__ __forceinline__ const void* rowp(const void* base, int row) {
    if constexpr (BF) return (const void*)((const u16*)base + (size_t)row * 512);
    else              return (const void*)((const float*)base + (size_t)row * 512);
}

// ---------- old (fallback) per-thread-row dots ----------
template<bool BF>
__device__ __forceinline__ void tridot(const void* vr, const void* vz, const void* vn,
                                       const float* __restrict__ sh,
                                       float& ar, float& az, float& an) {
    if constexpr (BF) {
        const u32* pr = (const u32*)vr;
        const u32* pz = (const u32*)vz;
        const u32* pn = (const u32*)vn;
        for (int k0 = 0; k0 < 512; k0 += 8) {
            float4 h0 = *(const float4*)&sh[k0];
            float4 h1 = *(const float4*)&sh[k0 + 4];
            int i0 = k0 >> 1;
            uint4 a = *(const uint4*)(pr + i0);
            uint4 c = *(const uint4*)(pz + i0);
            uint4 d = *(const uint4*)(pn + i0);
            ar += blo(a.x) * h0.x + bhi(a.x) * h0.y + blo(a.y) * h0.z + bhi(a.y) * h0.w
                + blo(a.z) * h1.x + bhi(a.z) * h1.y + blo(a.w) * h1.z + bhi(a.w) * h1.w;
            az += blo(c.x) * h0.x + bhi(c.x) * h0.y + blo(c.y) * h0.z + bhi(c.y) * h0.w
                + blo(c.z) * h1.x + bhi(c.z) * h1.y + blo(c.w) * h1.z + bhi(c.w) * h1.w;
            an += blo(d.x) * h0.x + bhi(d.x) * h0.y + blo(d.y) * h0.z + bhi(d.y) * h0.w
                + blo(d.z) * h1.x + bhi(d.z) * h1.y + blo(d.w) * h1.z + bhi(d.w) * h1.w;
        }
    } else {
        const float* pr = (const float*)vr;
        const float* pz = (const float*)vz;
        const float* pn = (const float*)vn;
        for (int k0 = 0; k0 < 512; k0 += 8) {
            float4 h0 = *(const float4*)&sh[k0];
            float4 h1 = *(const float4*)&sh[k0 + 4];
            float4 a0 = *(const float4*)(pr + k0), a1 = *(const float4*)(pr + k0 + 4);
            float4 c0 = *(const float4*)(pz + k0), c1 = *(const float4*)(pz + k0 + 4);
            float4 d0 = *(const float4*)(pn + k0), d1 = *(const float4*)(pn + k0 + 4);
            ar += a0.x * h0.x + a0.y * h0.y + a0.z * h0.z + a0.w * h0.w
                + a1.x * h1.x + a1.y * h1.y + a1.z * h1.z + a1.w * h1.w;
            az += c0.x * h0.x + c0.y * h0.y + c0.z * h0.z + c0.w * h0.w
                + c1.x * h1.x + c1.y * h1.y + c1.z * h1.z + c1.w * h1.w;
            an += d0.x * h0.x + d0.y * h0.y + d0.z * h0.z + d0.w * h0.w
                + d1.x * h1.x + d1.y * h1.y + d1.z * h1.z + d1.w * h1.w;
        }
    }
}

template<bool BF>
__device__ __forceinline__ float dot512(const void* vr, const float* __restrict__ sh) {
    float acc = 0.f;
    if constexpr (BF) {
        const u32* pr = (const u32*)vr;
        for (int k0 = 0; k0 < 512; k0 += 8) {
            float4 h0 = *(const float4*)&sh[k0];
            float4 h1 = *(const float4*)&sh[k0 + 4];
            uint4 a = *(const uint4*)(pr + (k0 >> 1));
            acc += blo(a.x) * h0.x + bhi(a.x) * h0.y + blo(a.y) * h0.z + bhi(a.y) * h0.w
                 + blo(a.z) * h1.x + bhi(a.z) * h1.y + blo(a.w) * h1.z + bhi(a.w) * h1.w;
        }
    } else {
        const float* pr = (const float*)vr;
        for (int k0 = 0; k0 < 512; k0 += 8) {
            float4 h0 = *(const float4*)&sh[k0];
            float4 h1 = *(const float4*)&sh[k0 + 4];
            float4 a0 = *(const float4*)(pr + k0), a1 = *(const float4*)(pr + k0 + 4);
            acc += a0.x * h0.x + a0.y * h0.y + a0.z * h0.z + a0.w * h0.w
                 + a1.x * h1.x + a1.y * h1.y + a1.z * h1.z + a1.w * h1.w;
        }
    }
    return acc;
}

// ---------- new: k-major panels (coalesced across lanes) ----------
// f32 layout:  float4 panel[(k>>2)*1536 + row]  holds W[row][k..k+3]
// bf16 layout: uint4  panel[(k>>3)*1536 + row]  holds W[row][k..k+7]
template<bool BF>
__device__ __forceinline__ void build_panels(const P& p, int tid) {
    if constexpr (BF) {
        for (int m = 0; m < 3; ++m) {
            const uint4* W = (const uint4*)p.W[2 + 2 * m];     // Whh0, Wih1, Whh1
            uint4* panel = (uint4*)p.ws + (size_t)m * (PANEL_ELEMS / 8);
            for (int i = tid; i < 1536 * 64; i += 512) {
                int r = i >> 6, k8 = i & 63;                   // src: row-major
                panel[(size_t)k8 * 1536 + r] = W[i];
            }
        }
    } else {
        for (int m = 0; m < 3; ++m) {
            const float4* W = (const float4*)p.W[2 + 2 * m];
            float4* panel = (float4*)p.ws + (size_t)m * (PANEL_ELEMS / 4);
            for (int i = tid; i < 1536 * 128; i += 512) {
                int r = i >> 7, k4 = i & 127;
                panel[(size_t)k4 * 1536 + r] = W[i];
            }
        }
    }
}

template<bool BF>
__device__ __forceinline__ void tridot_panel(const void* panel, int j,
                                             const float* __restrict__ sh,
                                             float& ar, float& az, float& an) {
    if constexpr (BF) {
        const uint4* pr = (const uint4*)panel + j;
        const uint4* pz = pr + 512;
        const uint4* pn = pr + 1024;
        for (int k0 = 0; k0 < 512; k0 += 8) {
            size_t o = (size_t)(k0 >> 3) * 1536;
            float4 h0 = *(const float4*)&sh[k0];
            float4 h1 = *(const float4*)&sh[k0 + 4];
            uint4 a = pr[o], c = pz[o], d = pn[o];
            ar += blo(a.x) * h0.x + bhi(a.x) * h0.y + blo(a.y) * h0.z + bhi(a.y) * h0.w
                + blo(a.z) * h1.x + bhi(a.z) * h1.y + blo(a.w) * h1.z + bhi(a.w) * h1.w;
            az += blo(c.x) * h0.x + bhi(c.x) * h0.y + blo(c.y) * h0.z + bhi(c.y) * h0.w
                + blo(c.z) * h1.x + bhi(c.z) * h1.y + blo(c.w) * h1.z + bhi(c.w) * h1.w;
            an += blo(d.x) * h0.x + bhi(d.x) * h0.y + blo(d.y) * h0.z + bhi(d.y) * h0.w
                + blo(d.z) * h1.x + bhi(d.z) * h1.y + blo(d.w) * h1.z + bhi(d.w) * h1.w;
        }
    } else {
        const float4* pr = (const float4*)panel + j;
        const float4* pz = pr + 512;
        const float4* pn = pr + 1024;
        for (int k0 = 0; k0 < 512; k0 += 8) {
            size_t o = (size_t)(k0 >> 2) * 1536;
            float4 h0 = *(const float4*)&sh[k0];
            float4 h1 = *(const float4*)&sh[k0 + 4];
            float4 a0 = pr[o], a1 = pr[o + 1536];
            float4 c0 = pz[o], c1 = pz[o + 1536];
            float4 d0 = pn[o], d1 = pn[o + 1536];
            ar += a0.x * h0.x + a0.y * h0.y + a0.z * h0.z + a0.w * h0.w
                + a1.x * h1.x + a1.y * h1.y + a1.z * h1.z + a1.w * h1.w;
            az += c0.x * h0.x + c0.y * h0.y + c0.z * h0.z + c0.w * h0.w
                + c1.x * h1.x + c1.y * h1.y + c1.z * h1.z + c1.w * h1.w;
            an += d0.x * h0.x + d0.y * h0.y + d0.z * h0.z + d0.w * h0.w
                + d1.x * h1.x + d1.y * h1.y + d1.z * h1.z + d1.w * h1.w;
        }
    }
}

// stable bitonic sort of 512 (key,idx) pairs, ascending, idx tie-break
__device__ void bitonic512(float* skey, int* sidx, int tid) {
    for (int k = 2; k <= 512; k <<= 1) {
        for (int j = k >> 1; j > 0; j >>= 1) {
            int ixj = tid ^ j;
            if (ixj > tid) {
                float ka = skey[tid], kb = skey[ixj];
                int ia = sidx[tid], ib = sidx[ixj];
                bool up = ((tid & k) == 0);
                bool agtb = (ka > kb) || (ka == kb && ia > ib);
                if (agtb == up) {
                    skey[tid] = kb; skey[ixj] = ka;
                    sidx[tid] = ib; sidx[ixj] = ia;
                }
            }
            __syncthreads();
        }
    }
}

template<bool BF, bool PAN>
__device__ void run_all(const P& p, Shm& s) {
    int b = blockIdx.x, tid = threadIdx.x;

    // build panels first so the writes drain under the preproc phase
    if constexpr (PAN) {
        build_panels<BF>(p, tid);
        __threadfence();
    }

    // ---------------- preproc ----------------
    float period = 2.0f / ldw<BF>(p.freq, b);
    float t = ldw<BF>(p.lc, (size_t)b * 3 * SS + tid);
    float m = ldw<BF>(p.lc, (size_t)b * 3 * SS + SS + tid);
    float ph0 = fmodf(t, period) / period;
    s.ph[tid] = ph0; s.mg[tid] = m;
    s.skey[tid] = ph0; s.sidx[tid] = tid;
    __syncthreads();
    bitonic512(s.skey, s.sidx, tid);

    // windowed robust threshold (circular +-2 in sorted order)
    {
        float pc = s.skey[tid];
        float wv[4], mv[4];
        float wsum = 0.f, wm = 0.f;
        const int offs[4] = {-2, -1, 1, 2};
#pragma unroll
        for (int c = 0; c < 4; ++c) {
            int jj = (tid + offs[c]) & 511;
            float d = s.skey[jj] - pc;
            float u = d - 0.5f; u = u - floorf(u);
            float dphi = u - 0.5f;
            float w = 0.75f * (1.0f - dphi * dphi);
            float mm = s.mg[s.sidx[jj]];
            wv[c] = w; mv[c] = mm;
            wsum += w; wm += w * mm;
        }
        float loc = wm / wsum;
        float s2 = 0.f;
#pragma unroll
        for (int c = 0; c < 4; ++c) { float dm = mv[c] - loc; s2 += dm * dm * wv[c]; }
        float scale = sqrtf(s2 / (wsum - 1.0f));
        s.sig[s.sidx[tid]] = loc + 5.0f * scale;
    }
    __syncthreads();
    s.vld[tid] = (s.mg[tid] > s.sig[tid]) ? 0.0f : 1.0f;
    __syncthreads();
    if (tid == 0) {
        float acc = 0.f;
        for (int i = 0; i < 512; ++i) acc += s.vld[i];
        s.nv = acc;
    }

    // kernel-smoothed magnitude on 50-grid (8 partials each)
    {
        int g = tid >> 3, part = tid & 7;
        if (g < 50) {
            float gv = (float)g * (1.0f / 49.0f);
            float num = 0.f, den = 0.f;
            int s0 = part * 64;
            for (int ss = s0; ss < s0 + 64; ++ss) {
                float d = gv - s.ph[ss];
                float c = cosf(TWO_PI * d);
                float K = expf((c - 1.0f) * 100.0f);
                float w = s.vld[ss] * K;
                den += w; num += w * s.mg[ss];
            }
            s.pn[g][part] = num; s.pd[g][part] = den;
        }
    }
    __syncthreads();
    if (tid < 50) {
        float num = 0.f, den = 0.f;
#pragma unroll
        for (int c = 0; c < 8; ++c) { num += s.pn[tid][c]; den += s.pd[tid][c]; }
        s.smoothv[tid] = num / den;
    }
    __syncthreads();
    if (tid == 0) {
        float best = s.smoothv[0]; int bi = 0;
        for (int g = 1; g < 50; ++g) if (s.smoothv[g] > best) { best = s.smoothv[g]; bi = g; }
        s.gshift = (float)bi * (1.0f / 49.0f);
    }
    __syncthreads();

    float p2 = s.ph[tid] - s.gshift;
    s.ph[tid] = p2;
    s.skey[tid] = (s.vld[tid] > 0.f) ? p2 : BIGF;
    s.sidx[tid] = tid;
    __syncthreads();
    bitonic512(s.skey, s.sidx, tid);

    {   // gather into sorted arrays
        int o = s.sidx[tid];
        s.ps2[tid] = s.ph[o]; s.ms2[tid] = s.mg[o]; s.vs2[tid] = s.vld[o];
    }

    // ---------------- fused 2-layer GRU ----------------
    int j = tid;
    float wr0[33], wz0[33], wn0[33];
#pragma unroll
    for (int d = 0; d < 33; ++d) {
        wr0[d] = ldw<BF>(p.W[0], (size_t)j * 33 + d);
        wz0[d] = ldw<BF>(p.W[0], ((size_t)j + 512) * 33 + d);
        wn0[d] = ldw<BF>(p.W[0], ((size_t)j + 1024) * 33 + d);
    }
    float bi0r = ldw<BF>(p.W[1], j), bi0z = ldw<BF>(p.W[1], j + 512), bi0n = ldw<BF>(p.W[1], j + 1024);
    float bh0r = ldw<BF>(p.W[3], j), bh0z = ldw<BF>(p.W[3], j + 512), bh0n = ldw<BF>(p.W[3], j + 1024);
    float bi1r = ldw<BF>(p.W[5], j), bi1z = ldw<BF>(p.W[5], j + 512), bi1n = ldw<BF>(p.W[5], j + 1024);
    float bh1r = ldw<BF>(p.W[7], j), bh1z = ldw<BF>(p.W[7], j + 512), bh1n = ldw<BF>(p.W[7], j + 1024);

    // panel base pointers (PAN) or row pointers (fallback)
    const void *pan0 = nullptr, *pan1x = nullptr, *pan1h = nullptr;
    const void *w0r = nullptr, *w0z = nullptr, *w0n = nullptr;
    const void *x1r = nullptr, *x1z = nullptr, *x1n = nullptr;
    const void *w1r = nullptr, *w1z = nullptr, *w1n = nullptr;
    if constexpr (PAN) {
        if constexpr (BF) {
            pan0  = (const void*)((const u16*)p.ws);
            pan1x = (const void*)((const u16*)p.ws + (size_t)PANEL_ELEMS);
            pan1h = (const void*)((const u16*)p.ws + (size_t)2 * PANEL_ELEMS);
        } else {
            pan0  = (const void*)((const float*)p.ws);
            pan1x = (const void*)((const float*)p.ws + (size_t)PANEL_ELEMS);
            pan1h = (const void*)((const float*)p.ws + (size_t)2 * PANEL_ELEMS);
        }
    } else {
        w0r = rowp<BF>(p.W[2], j);
        w0z = rowp<BF>(p.W[2], j + 512);
        w0n = rowp<BF>(p.W[2], j + 1024);
        x1r = rowp<BF>(p.W[4], j);
        x1z = rowp<BF>(p.W[4], j + 512);
        x1n = rowp<BF>(p.W[4], j + 1024);
        w1r = rowp<BF>(p.W[6], j);
        w1z = rowp<BF>(p.W[6], j + 512);
        w1n = rowp<BF>(p.W[6], j + 1024);
    }

    s.h0[j] = 0.f; s.h1[j] = 0.f;
    float cacc = 0.f;
    __syncthreads();

    for (int tt = 0; tt < 512; ++tt) {
        if (j < 16) {
            float ang = TWO_PI * s.ps2[tt] * (float)(j + 1);
            float sv, cv;
            sincosf(ang, &sv, &cv);
            s.eL[j] = cv; s.eL[16 + j] = sv;
        }
        if (j == 32) s.eL[32] = s.ms2[tt];
        __syncthreads();                           // (A) eL ready
        // layer 0
        float xr = bi0r, xz = bi0z, xn = bi0n;
#pragma unroll
        for (int d = 0; d < 33; ++d) {
            float e = s.eL[d];
            xr += wr0[d] * e; xz += wz0[d] * e; xn += wn0[d] * e;
        }
        float ar = bh0r, az = bh0z, an = bh0n;
        if constexpr (PAN) tridot_panel<BF>(pan0, j, s.h0, ar, az, an);
        else               tridot<BF>(w0r, w0z, w0n, s.h0, ar, az, an);
        float h0prev = s.h0[j];
        float r0 = 1.0f / (1.0f + expf(-(xr + ar)));
        float z0 = 1.0f / (1.0f + expf(-(xz + az)));
        float n0 = tanhf(xn + r0 * an);
        float nh0 = (1.0f - z0) * n0 + z0 * h0prev;
        __syncthreads();                           // (B) h0 reads done
        s.h0[j] = nh0;
        __syncthreads();                           // (C) h0 ready
        // layer 1
        float yr = bi1r, yz = bi1z, yn = bi1n;
        float cr = bh1r, cz = bh1z, cn = bh1n;
        if constexpr (PAN) {
            tridot_panel<BF>(pan1x, j, s.h0, yr, yz, yn);
            tridot_panel<BF>(pan1h, j, s.h1, cr, cz, cn);
        } else {
            tridot<BF>(x1r, x1z, x1n, s.h0, yr, yz, yn);
            tridot<BF>(w1r, w1z, w1n, s.h1, cr, cz, cn);
        }
        float h1prev = s.h1[j];
        float r1 = 1.0f / (1.0f + expf(-(yr + cr)));
        float z1 = 1.0f / (1.0f + expf(-(yz + cz)));
        float n1 = tanhf(yn + r1 * cn);
        float nh1 = (1.0f - z1) * n1 + z1 * h1prev;
        cacc += s.vs2[tt] * nh1;
        __syncthreads();                           // (D) h1 reads done
        s.h1[j] = nh1;
    }
    __syncthreads();

    // ---------------- MLP head ----------------
    s.h0[j] = cacc / s.nv;                         // ctx
    __syncthreads();
    float a1 = ldw<BF>(p.W[9], j) + dot512<BF>(rowp<BF>(p.W[8], j), s.h0);
    float g = 0.5f * a1 * (1.0f + erff(a1 * 0.70710678118654752440f));
    __syncthreads();
    s.h1[j] = g;
    __syncthreads();
    if (j < 16) {
        float a2 = ldw<BF>(p.W[11], j) + dot512<BF>(rowp<BF>(p.W[10], j), s.h1);
        if constexpr (BF) ((u16*)p.out)[(size_t)b * 16 + j] = f2b(a2);
        else              ((float*)p.out)[(size_t)b * 16 + j] = a2;
    }
}

__global__ __launch_bounds__(512, 2) void fused_kernel(P p) {
    __shared__ Shm s;
    bool bf = inputs_are_bf16(p.freq);
    if (bf) {
        if (p.ws && p.ws_size >= 3ull * PANEL_ELEMS * 2) run_all<true, true>(p, s);
        else                                             run_all<true, false>(p, s);
    } else {
        if (p.ws && p.ws_size >= 3ull * PANEL_ELEMS * 4) run_all<false, true>(p, s);
        else                                             run_all<false, false>(p, s);
    }
}

extern "C" void kernel_launch(void* const* d_in, const int* in_sizes, int n_in,
                              void* d_out, int out_size, void* d_ws, size_t ws_size,
                              hipStream_t stream) {
    P p;
    p.lc = d_in[0];
    p.freq = d_in[2];
    for (int i = 0; i < 12; ++i) p.W[i] = d_in[3 + i];
    p.out = d_out;
    p.ws = d_ws;
    p.ws_size = (unsigned long long)ws_size;
    fused_kernel<<<BB, 512, 0, stream>>>(p);
    (void)in_sizes; (void)n_in; (void)out_size;
}